// Round 4
// baseline (855.647 us; speedup 1.0000x reference)
//
#include <hip/hip_runtime.h>

// Problem constants (B, LQ, LK, D fixed by the reference)
#define DDIM 1024
#define LQN  2048
#define LKN  2048
#define BBAT 8

// ROUND-3 FINDING: all float tensors are f32 (reference dtype), mask int32,
// output f32. bf16 misread of f32 inputs was the NaN source in rounds 0-3.
// Pipeline: cast f32->bf16 during LDS staging, bf16 MFMA, f32 accum/output.

typedef short bf16x8 __attribute__((ext_vector_type(8)));
typedef float f32x4  __attribute__((ext_vector_type(4)));

__device__ __forceinline__ unsigned short f2bf(float f) {
    union { float f; unsigned int i; } x; x.f = f;
    unsigned int r = (x.i + 0x7fffu + ((x.i >> 16) & 1u)) >> 16;  // RNE
    return (unsigned short)r;
}
__device__ __forceinline__ bf16x8 cvt8(const float* p) {
    float4 x0 = *(const float4*)p;
    float4 x1 = *(const float4*)(p + 4);
    bf16x8 r;
    r[0] = (short)f2bf(x0.x); r[1] = (short)f2bf(x0.y);
    r[2] = (short)f2bf(x0.z); r[3] = (short)f2bf(x0.w);
    r[4] = (short)f2bf(x1.x); r[5] = (short)f2bf(x1.y);
    r[6] = (short)f2bf(x1.z); r[7] = (short)f2bf(x1.w);
    return r;
}

// NT GEMM: C[M,N] = A[M,K] * Bt[N,K]^T. 128x128 tile, BK=32, 256 thr = 4 waves
// (2x2), each wave 64x64 via 4x4 mfma_f32_16x16x32_bf16. Register staging with
// in-flight f32->bf16 conversion where the operand is f32.
// MODE 0: Qp/Kp = X*W^T + b      A=f32 X, B=f32 W,  out bf16, bias[col] (f32)
// MODE 1: Vt = Wv*Kp^T + bv      A=f32 Wv, B=bf16,  out bf16, bias[row] (f32)
// MODE 2: S = Qp*Kp^T *s, mask   A=bf16, B=bf16,    out f32, batched via z
// MODE 3: O = P*Vt^T             A=f32 P, B=bf16,   out f32, batched via z
template<int MODE>
__global__ __launch_bounds__(256)
void gemm_nt(const void* __restrict__ Ab,
             const void* __restrict__ Bb,
             const float* __restrict__ bias,
             const int* __restrict__ mask,
             void* __restrict__ out)
{
    constexpr int  K    = (MODE == 3) ? LKN : DDIM;
    constexpr int  LDA  = K;
    constexpr int  LDB  = K;
    constexpr bool A_F  = (MODE != 2);   // A operand is f32
    constexpr bool B_F  = (MODE == 0);   // B operand is f32

    __shared__ unsigned short lA[128 * 32];
    __shared__ unsigned short lB[128 * 32];

    const int t    = threadIdx.x;
    const int lane = t & 63;
    const int wave = t >> 6;
    const int wm   = wave >> 1;
    const int wn   = wave & 1;

    const int bm = blockIdx.y;
    const int bn = blockIdx.x;
    const int z  = blockIdx.z;

    const float*          Af = (const float*)Ab;
    const unsigned short* Ah = (const unsigned short*)Ab;
    const float*          Bf = (const float*)Bb;
    const unsigned short* Bh = (const unsigned short*)Bb;
    if (MODE == 2) { Ah += (long)z * LQN * DDIM; Bh += (long)z * LKN * DDIM; }
    if (MODE == 3) { Af += (long)z * LQN * LKN;  Bh += (long)z * DDIM * LKN; }

    // staging: thread t covers rows (t>>2) and (t>>2)+64, k-chunk (t&3)*8
    const int  srow  = t >> 2;
    const int  skk   = (t & 3) * 8;
    const long arow0 = (long)(bm * 128 + srow) * LDA + skk;
    const long arow1 = arow0 + 64L * LDA;
    const long brow0 = (long)(bn * 128 + srow) * LDB + skk;
    const long brow1 = brow0 + 64L * LDB;
    unsigned short* lAp = lA + t * 8;   // 16B per thread, contiguous
    unsigned short* lBp = lB + t * 8;

    f32x4 acc[4][4];
    #pragma unroll
    for (int i = 0; i < 4; ++i)
        #pragma unroll
        for (int j = 0; j < 4; ++j)
            acc[i][j] = (f32x4)(0.0f);

    const int quad = lane >> 4;
    const int l15  = lane & 15;

    for (int k0 = 0; k0 < K; k0 += 32) {
        bf16x8 a0, a1, b0, b1;
        if (A_F) { a0 = cvt8(Af + arow0 + k0); a1 = cvt8(Af + arow1 + k0); }
        else     { a0 = *(const bf16x8*)(Ah + arow0 + k0);
                   a1 = *(const bf16x8*)(Ah + arow1 + k0); }
        if (B_F) { b0 = cvt8(Bf + brow0 + k0); b1 = cvt8(Bf + brow1 + k0); }
        else     { b0 = *(const bf16x8*)(Bh + brow0 + k0);
                   b1 = *(const bf16x8*)(Bh + brow1 + k0); }

        __syncthreads();                       // prev iter's LDS reads done
        *(bf16x8*)lAp          = a0;
        *(bf16x8*)(lAp + 2048) = a1;           // +2048 shorts = rows 64..127
        *(bf16x8*)lBp          = b0;
        *(bf16x8*)(lBp + 2048) = b1;
        __syncthreads();                       // stores visible to all waves

        bf16x8 af[4], bfv[4];
        #pragma unroll
        for (int i = 0; i < 4; ++i)
            af[i] = *(const bf16x8*)&lA[(wm * 64 + i * 16 + l15) * 32 + quad * 8];
        #pragma unroll
        for (int j = 0; j < 4; ++j)
            bfv[j] = *(const bf16x8*)&lB[(wn * 64 + j * 16 + l15) * 32 + quad * 8];

        #pragma unroll
        for (int i = 0; i < 4; ++i)
            #pragma unroll
            for (int j = 0; j < 4; ++j)
                acc[i][j] = __builtin_amdgcn_mfma_f32_16x16x32_bf16(af[i], bfv[j], acc[i][j], 0, 0, 0);
    }

    // epilogue: C/D layout col=lane&15, row=quad*4+r  [measured m89/m91]
    #pragma unroll
    for (int i = 0; i < 4; ++i) {
        #pragma unroll
        for (int j = 0; j < 4; ++j) {
            const int grow = bm * 128 + wm * 64 + i * 16 + quad * 4;
            const int gcol = bn * 128 + wn * 64 + j * 16 + l15;
            if (MODE == 0) {
                const float bc = bias[gcol];
                #pragma unroll
                for (int r = 0; r < 4; ++r)
                    ((unsigned short*)out)[(long)(grow + r) * DDIM + gcol] =
                        f2bf(acc[i][j][r] + bc);
            } else if (MODE == 1) {
                const int b2 = gcol >> 11;        // in-group batch
                const int lk = gcol & 2047;
                #pragma unroll
                for (int r = 0; r < 4; ++r) {
                    const float bc = bias[grow + r];
                    ((unsigned short*)out)[(long)b2 * DDIM * LKN +
                                           (long)(grow + r) * LKN + lk] =
                        f2bf(acc[i][j][r] + bc);
                }
            } else if (MODE == 2) {
                const int mv = mask[z * LKN + gcol];
                #pragma unroll
                for (int r = 0; r < 4; ++r) {
                    float v = acc[i][j][r] * 0.03125f;   // 1/sqrt(1024)
                    if (mv == 0) v = -1e9f;
                    ((float*)out)[(long)z * LQN * LKN +
                                  (long)(grow + r) * LKN + gcol] = v;
                }
            } else {
                #pragma unroll
                for (int r = 0; r < 4; ++r)
                    ((float*)out)[(long)z * LQN * DDIM +
                                  (long)(grow + r) * DDIM + gcol] = acc[i][j][r];
            }
        }
    }
}

// in-place f32 row softmax over LKN scores; one block (256 thr) per row
__global__ __launch_bounds__(256)
void softmax_rows(float* __restrict__ P)
{
    const int t = threadIdx.x;
    const long base = (long)blockIdx.x * LKN + t * 8;

    float4 r0 = *(const float4*)&P[base];
    float4 r1 = *(const float4*)&P[base + 4];
    float v[8] = { r0.x, r0.y, r0.z, r0.w, r1.x, r1.y, r1.z, r1.w };

    float m = -3.0e38f;
    #pragma unroll
    for (int i = 0; i < 8; ++i) m = fmaxf(m, v[i]);
    #pragma unroll
    for (int off = 32; off >= 1; off >>= 1) m = fmaxf(m, __shfl_xor(m, off, 64));
    __shared__ float redm[4];
    if ((t & 63) == 0) redm[t >> 6] = m;
    __syncthreads();
    m = fmaxf(fmaxf(redm[0], redm[1]), fmaxf(redm[2], redm[3]));

    float s = 0.0f;
    #pragma unroll
    for (int i = 0; i < 8; ++i) { v[i] = __expf(v[i] - m); s += v[i]; }
    #pragma unroll
    for (int off = 32; off >= 1; off >>= 1) s += __shfl_xor(s, off, 64);
    __shared__ float reds[4];
    if ((t & 63) == 0) reds[t >> 6] = s;
    __syncthreads();
    s = reds[0] + reds[1] + reds[2] + reds[3];

    const float inv = 1.0f / s;   // s >= 1 always (max element contributes 1)
    r0.x = v[0] * inv; r0.y = v[1] * inv; r0.z = v[2] * inv; r0.w = v[3] * inv;
    r1.x = v[4] * inv; r1.y = v[5] * inv; r1.z = v[6] * inv; r1.w = v[7] * inv;
    *(float4*)&P[base]     = r0;
    *(float4*)&P[base + 4] = r1;
}

extern "C" void kernel_launch(void* const* d_in, const int* in_sizes, int n_in,
                              void* d_out, int out_size, void* d_ws, size_t ws_size,
                              hipStream_t stream)
{
    (void)in_sizes; (void)n_in; (void)out_size;

    const float* key   = (const float*)d_in[0];
    const float* query = (const float*)d_in[1];
    const int*   mask  = (const int*)d_in[2];
    const float* Wq    = (const float*)d_in[3];
    const float* bq    = (const float*)d_in[4];
    const float* Wk    = (const float*)d_in[5];
    const float* bk    = (const float*)d_in[6];
    const float* Wv    = (const float*)d_in[7];
    const float* bv    = (const float*)d_in[8];

    float* outO = (float*)d_out;                          // [B,LQ,D]  f32
    float* outP = outO + (size_t)BBAT * LQN * DDIM;       // [B,LQ,LK] f32

    // Per-batch bf16 scratch: Qp_b + Kp_b + Vt_b = 3 * 2048*1024*2 B = 12 MiB
    const size_t perBatch = (size_t)3 * LKN * DDIM * sizeof(unsigned short);
    int g = (int)(ws_size / perBatch);
    if (g > BBAT) g = BBAT;
    if (g < 1)    g = 1;

    dim3 blk(256, 1, 1);

    for (int b0 = 0; b0 < BBAT; b0 += g) {
        const int gl = (BBAT - b0 < g) ? (BBAT - b0) : g;

        unsigned short* Qp = (unsigned short*)d_ws;            // [gl*LQ, D] bf16
        unsigned short* Kp = Qp + (size_t)gl * LQN * DDIM;     // [gl*LK, D] bf16
        unsigned short* Vt = Kp + (size_t)gl * LKN * DDIM;     // [gl, D, LK] bf16

        // Qp = query[b0..)*Wq^T + bq   (M=gl*2048, N=1024, K=1024)
        gemm_nt<0><<<dim3(8, gl * 16, 1), blk, 0, stream>>>(
            query + (size_t)b0 * LQN * DDIM, Wq, bq, nullptr, Qp);

        // Kp = key[b0..)*Wk^T + bk
        gemm_nt<0><<<dim3(8, gl * 16, 1), blk, 0, stream>>>(
            key + (size_t)b0 * LKN * DDIM, Wk, bk, nullptr, Kp);

        // Vt[z][d][lk] = Wv*Kp^T + bv   (M=1024, N=gl*2048, K=1024)
        gemm_nt<1><<<dim3(gl * 16, 8, 1), blk, 0, stream>>>(
            Wv, Kp, bv, nullptr, Vt);

        // S[z] = Qp[z]*Kp[z]^T * scale, mask fill  (per z: 2048x2048, K=1024)
        gemm_nt<2><<<dim3(16, 16, gl), blk, 0, stream>>>(
            Qp, Kp, nullptr, mask + (size_t)b0 * LKN,
            outP + (size_t)b0 * LQN * LKN);

        // softmax rows in place (f32)
        softmax_rows<<<dim3(gl * LQN, 1, 1), blk, 0, stream>>>(
            outP + (size_t)b0 * LQN * LKN);

        // O[z] = P[z]*Vt[z]^T   (per z: M=2048, N=1024, K=2048)
        gemm_nt<3><<<dim3(8, 16, gl), blk, 0, stream>>>(
            outP + (size_t)b0 * LQN * LKN, Vt, nullptr, nullptr,
            outO + (size_t)b0 * LQN * DDIM);
    }
}